// Round 4
// baseline (17.093 us; speedup 1.0000x reference)
//
#include <hip/hip_runtime.h>

// CGWeight: out[k] = nan_to_num( sum_c w[c] * sum_{i,j} CG_c[i,j,k] * A[la_c][i] * H[lh_c][j] )
// L_OUT = 2. ALL Clebsch-Gordan math done at COMPILE TIME (constexpr Racah +
// e3nn basis change, verified absmax=0.0 in R2/R3). Runtime: one 64-lane wave,
// fully-unrolled vector loads of a compacted SoA table, ~45 FMAs/lane.

namespace cgc {

constexpr int C_LA[16] = {0,1,1,1,2,2,2,2,2,3,3,3,3,4,4,4};
constexpr int C_LH[16] = {2,1,2,3,0,1,2,3,4,1,2,3,4,2,3,4};
constexpr int ABASE[5] = {0,1,4,9,16};   // prefix offsets of concatenated l=0..4 vectors

constexpr double FACT[16] = {
    1.0, 1.0, 2.0, 6.0, 24.0, 120.0, 720.0, 5040.0,
    40320.0, 362880.0, 3628800.0, 39916800.0, 479001600.0,
    6227020800.0, 87178291200.0, 1307674368000.0};

constexpr double csqrt(double x) {
    if (x <= 0.0) return 0.0;
    double s = 1.0, v = x;
    while (v > 4.0)  { v *= 0.25; s *= 2.0; }
    while (v < 0.25) { v *= 4.0;  s *= 0.5; }
    double g = 1.0;
    for (int i = 0; i < 10; ++i) g = 0.5 * (g + v / g);
    return g * s;
}

constexpr double su2cg(int j1, int m1, int j2, int m2, int j3, int m3) {
    if (m1 + m2 != m3) return 0.0;
    int vmin = -j1 + j2 + m3; if (-j1 + m1 > vmin) vmin = -j1 + m1; if (vmin < 0) vmin = 0;
    int vmax = j2 + j3 + m1; if (j3 - j1 + j2 < vmax) vmax = j3 - j1 + j2; if (j3 + m3 < vmax) vmax = j3 + m3;
    if (vmax < vmin) return 0.0;
    double C = csqrt((2.0 * j3 + 1.0)
                     * FACT[j3 + j1 - j2] * FACT[j3 - j1 + j2] * FACT[j1 + j2 - j3]
                     / FACT[j1 + j2 + j3 + 1]
                     * FACT[j3 + m3] * FACT[j3 - m3]
                     / (FACT[j1 + m1] * FACT[j1 - m1] * FACT[j2 + m2] * FACT[j2 - m2]));
    double S = 0.0;
    for (int v = vmin; v <= vmax; ++v) {
        double t = FACT[j2 + j3 + m1 - v] * FACT[j1 - m1 + v]
                 / (FACT[v] * FACT[j3 - j1 + j2 - v] * FACT[j3 + m3 - v] * FACT[v + j1 - j2 - m3]);
        S += ((v + j2 + m2) & 1) ? -t : t;
    }
    return C * S;
}

struct CD { double re, im; };
constexpr CD cmul(CD a, CD b) { return {a.re*b.re - a.im*b.im, a.re*b.im + a.im*b.re}; }

// Nonzero rows of column c of the e3nn real->complex basis matrix Q_l.
constexpr int q_col(int l, int c, int* rows, CD* vals) {
    CD ph{1.0, 0.0};                           // (-i)^l
    switch (l & 3) {
        case 0: ph = { 1.0,  0.0}; break;
        case 1: ph = { 0.0, -1.0}; break;
        case 2: ph = {-1.0,  0.0}; break;
        default: ph = { 0.0,  1.0}; break;
    }
    const double is2 = 0.70710678118654752440;
    int mu = c - l;
    if (mu == 0) { rows[0] = l; vals[0] = ph; return 1; }
    int amu = mu > 0 ? mu : -mu;
    double sgn = (amu & 1) ? -1.0 : 1.0;       // (-1)^|mu|
    rows[0] = l - amu;
    rows[1] = l + amu;
    if (mu > 0) {
        vals[0] = cmul(ph, {is2, 0.0});
        vals[1] = cmul(ph, {sgn * is2, 0.0});
    } else {
        vals[0] = cmul(ph, {0.0, -is2});
        vals[1] = cmul(ph, {0.0, sgn * is2});
    }
    return 2;
}

#define MAXE 532
// SoA, vector-load-friendly:
struct Tables {
    int n;
    int   idx[MAXE];                              // aoff | hoff<<8 | wi<<16
    alignas(16) float cg4[MAXE][4];               // k = 0..3  (one dwordx4)
    float cg1[MAXE];                              // k = 4
};

constexpr Tables build() {
    Tables T{};
    int r3[5][2]{}; CD v3[5][2]{}; int n3[5]{};
    for (int k = 0; k < 5; ++k) n3[k] = q_col(2, k, r3[k], v3[k]);
    int e = 0;
    for (int c = 0; c < 16; ++c) {
        const int la = C_LA[c], lh = C_LH[c];
        double stab[9][9]{};
        for (int i1 = 0; i1 < 2*la+1; ++i1)
            for (int i2 = 0; i2 < 2*lh+1; ++i2) {
                int m1 = i1 - la, m2 = i2 - lh, m3 = m1 + m2;
                if (m3 >= -2 && m3 <= 2) stab[i1][i2] = su2cg(la, m1, lh, m2, 2, m3);
            }
        for (int i = 0; i < 2*la+1; ++i) {
            int r1[2]{}; CD v1[2]{}; const int n1 = q_col(la, i, r1, v1);
            for (int j = 0; j < 2*lh+1; ++j) {
                int r2[2]{}; CD v2[2]{}; const int n2 = q_col(lh, j, r2, v2);
                double outk[5]{};
                bool any = false;
                for (int k = 0; k < 5; ++k) {
                    double acc = 0.0;
                    for (int a = 0; a < n1; ++a)
                        for (int b = 0; b < n2; ++b) {
                            const int m3 = (r1[a] - la) + (r2[b] - lh);
                            for (int q = 0; q < n3[k]; ++q) {
                                if (r3[k][q] - 2 != m3) continue;
                                CD t = cmul(v1[a], v2[b]);
                                acc += (t.re * v3[k][q].re + t.im * v3[k][q].im)
                                       * stab[r1[a]][r2[b]];   // Re(Q1 Q2 conj(Q3)) * su2cg
                            }
                        }
                    outk[k] = acc;
                    if (acc != 0.0) any = true;
                }
                if (any) {
                    T.idx[e] = (ABASE[la] + i) | ((ABASE[lh] + j) << 8) | (c << 16);
                    for (int k = 0; k < 4; ++k) T.cg4[e][k] = (float)outk[k];
                    T.cg1[e] = (float)outk[4];
                    ++e;
                }
            }
        }
    }
    T.n = e;
    return T;
}

constexpr Tables T_HOST = build();
constexpr int N_ENT = T_HOST.n;          // COMPILE-TIME trip count -> full unroll

} // namespace cgc

__constant__ cgc::Tables g_tab = cgc::T_HOST;

__global__ __launch_bounds__(64) void cgweight_kernel(
    const float* __restrict__ a0, const float* __restrict__ a1,
    const float* __restrict__ a2, const float* __restrict__ a3,
    const float* __restrict__ a4,
    const float* __restrict__ h0, const float* __restrict__ h1,
    const float* __restrict__ h2, const float* __restrict__ h3,
    const float* __restrict__ h4,
    const float* __restrict__ w, float* __restrict__ out) {

    __shared__ float sA[25], sH[25], sW[16];
    const float* A[5] = {a0, a1, a2, a3, a4};
    const float* H[5] = {h0, h1, h2, h3, h4};
    const int END[5] = {1, 4, 9, 16, 25};

    const int t = threadIdx.x;   // one 64-lane wave
    if (t < 25) {
        int l = 0;
        while (l < 4 && t >= END[l]) ++l;
        sA[t] = A[l][t - (END[l] - (2*l+1))];
    } else if (t < 50) {
        int u = t - 25;
        int l = 0;
        while (l < 4 && u >= END[l]) ++l;
        sH[u] = H[l][u - (END[l] - (2*l+1))];
    }
    if (t >= 48) sW[t - 48] = w[t - 48];
    __syncthreads();

    float c0 = 0.f, c1 = 0.f, c2 = 0.f, c3 = 0.f, c4 = 0.f;

    constexpr int NIT = (cgc::N_ENT + 63) / 64;
#pragma unroll
    for (int it = 0; it < NIT; ++it) {
        const int e = t + it * 64;
        if (e < cgc::N_ENT) {            // divergent only in the last iteration
            const int   id = g_tab.idx[e];
            const float4 q = *reinterpret_cast<const float4*>(g_tab.cg4[e]);
            const float q4 = g_tab.cg1[e];
            const float p  = sA[id & 255] * sH[(id >> 8) & 255] * sW[id >> 16];
            c0 += q.x * p;
            c1 += q.y * p;
            c2 += q.z * p;
            c3 += q.w * p;
            c4 += q4  * p;
        }
    }

    // 64-lane butterfly reduce
    float acc[5] = {c0, c1, c2, c3, c4};
#pragma unroll
    for (int k = 0; k < 5; ++k) {
        float v = acc[k];
#pragma unroll
        for (int off = 32; off > 0; off >>= 1)
            v += __shfl_down(v, off, 64);
        acc[k] = v;
    }

    if (t == 0) {
#pragma unroll
        for (int k = 0; k < 5; ++k) {
            float f = acc[k];
            out[k] = (f != f) ? 0.0f : f;   // nan_to_num
        }
    }
}

extern "C" void kernel_launch(void* const* d_in, const int* in_sizes, int n_in,
                              void* d_out, int out_size, void* d_ws, size_t ws_size,
                              hipStream_t stream) {
    const float* a0 = (const float*)d_in[0];
    const float* a1 = (const float*)d_in[1];
    const float* a2 = (const float*)d_in[2];
    const float* a3 = (const float*)d_in[3];
    const float* a4 = (const float*)d_in[4];
    const float* h0 = (const float*)d_in[5];
    const float* h1 = (const float*)d_in[6];
    const float* h2 = (const float*)d_in[7];
    const float* h3 = (const float*)d_in[8];
    const float* h4 = (const float*)d_in[9];
    const float* w  = (const float*)d_in[10];
    float* out = (float*)d_out;

    cgweight_kernel<<<1, 64, 0, stream>>>(a0, a1, a2, a3, a4,
                                          h0, h1, h2, h3, h4, w, out);
}

// Round 5
// 9.611 us; speedup vs baseline: 1.7786x; 1.7786x over previous
//
#include <hip/hip_runtime.h>

// CGWeight: out[k] = nan_to_num( sum_c w[c] * sum_{i,j} CG_c[i,j,k] * A[la_c][i] * H[lh_c][j] )
// L_OUT = 2. ALL Clebsch-Gordan math done at COMPILE TIME (constexpr Racah +
// e3nn basis change; verified absmax=0.0 in R2/R3/R4).
// Runtime design (cold-cache-optimal, single wave):
//   - ONE memory round: 3 input loads + 21 branch-free table loads, all
//     clustered before a single wait (the harness's interleaved 268MB fills
//     evict L2/L3 between replays, so serialized miss-rounds dominate).
//   - No LDS, no barriers: in-wave __shfl (ds_bpermute) gathers A[i]*H[j]*w[c].

namespace cgc {

constexpr int C_LA[16] = {0,1,1,1,2,2,2,2,2,3,3,3,3,4,4,4};
constexpr int C_LH[16] = {2,1,2,3,0,1,2,3,4,1,2,3,4,2,3,4};
constexpr int ABASE[5] = {0,1,4,9,16};   // prefix offsets of concatenated l=0..4 vectors

constexpr double FACT[16] = {
    1.0, 1.0, 2.0, 6.0, 24.0, 120.0, 720.0, 5040.0,
    40320.0, 362880.0, 3628800.0, 39916800.0, 479001600.0,
    6227020800.0, 87178291200.0, 1307674368000.0};

constexpr double csqrt(double x) {
    if (x <= 0.0) return 0.0;
    double s = 1.0, v = x;
    while (v > 4.0)  { v *= 0.25; s *= 2.0; }
    while (v < 0.25) { v *= 4.0;  s *= 0.5; }
    double g = 1.0;
    for (int i = 0; i < 10; ++i) g = 0.5 * (g + v / g);
    return g * s;
}

constexpr double su2cg(int j1, int m1, int j2, int m2, int j3, int m3) {
    if (m1 + m2 != m3) return 0.0;
    int vmin = -j1 + j2 + m3; if (-j1 + m1 > vmin) vmin = -j1 + m1; if (vmin < 0) vmin = 0;
    int vmax = j2 + j3 + m1; if (j3 - j1 + j2 < vmax) vmax = j3 - j1 + j2; if (j3 + m3 < vmax) vmax = j3 + m3;
    if (vmax < vmin) return 0.0;
    double C = csqrt((2.0 * j3 + 1.0)
                     * FACT[j3 + j1 - j2] * FACT[j3 - j1 + j2] * FACT[j1 + j2 - j3]
                     / FACT[j1 + j2 + j3 + 1]
                     * FACT[j3 + m3] * FACT[j3 - m3]
                     / (FACT[j1 + m1] * FACT[j1 - m1] * FACT[j2 + m2] * FACT[j2 - m2]));
    double S = 0.0;
    for (int v = vmin; v <= vmax; ++v) {
        double t = FACT[j2 + j3 + m1 - v] * FACT[j1 - m1 + v]
                 / (FACT[v] * FACT[j3 - j1 + j2 - v] * FACT[j3 + m3 - v] * FACT[v + j1 - j2 - m3]);
        S += ((v + j2 + m2) & 1) ? -t : t;
    }
    return C * S;
}

struct CD { double re, im; };
constexpr CD cmul(CD a, CD b) { return {a.re*b.re - a.im*b.im, a.re*b.im + a.im*b.re}; }

// Nonzero rows of column c of the e3nn real->complex basis matrix Q_l.
constexpr int q_col(int l, int c, int* rows, CD* vals) {
    CD ph{1.0, 0.0};                           // (-i)^l
    switch (l & 3) {
        case 0: ph = { 1.0,  0.0}; break;
        case 1: ph = { 0.0, -1.0}; break;
        case 2: ph = {-1.0,  0.0}; break;
        default: ph = { 0.0,  1.0}; break;
    }
    const double is2 = 0.70710678118654752440;
    int mu = c - l;
    if (mu == 0) { rows[0] = l; vals[0] = ph; return 1; }
    int amu = mu > 0 ? mu : -mu;
    double sgn = (amu & 1) ? -1.0 : 1.0;       // (-1)^|mu|
    rows[0] = l - amu;
    rows[1] = l + amu;
    if (mu > 0) {
        vals[0] = cmul(ph, {is2, 0.0});
        vals[1] = cmul(ph, {sgn * is2, 0.0});
    } else {
        vals[0] = cmul(ph, {0.0, -is2});
        vals[1] = cmul(ph, {0.0, sgn * is2});
    }
    return 2;
}

// padded capacity: ceil(532/64)*64
#define MAXP 576
struct Tables {
    int n;
    int   idx[MAXP];                 // aoff | hoff<<8 | wi<<16   (pad: 0)
    alignas(16) float cg4[MAXP][4];  // k = 0..3                  (pad: 0)
    float cg1[MAXP];                 // k = 4                     (pad: 0)
};

constexpr Tables build() {
    Tables T{};
    int r3[5][2]{}; CD v3[5][2]{}; int n3[5]{};
    for (int k = 0; k < 5; ++k) n3[k] = q_col(2, k, r3[k], v3[k]);
    int e = 0;
    for (int c = 0; c < 16; ++c) {
        const int la = C_LA[c], lh = C_LH[c];
        double stab[9][9]{};
        for (int i1 = 0; i1 < 2*la+1; ++i1)
            for (int i2 = 0; i2 < 2*lh+1; ++i2) {
                int m1 = i1 - la, m2 = i2 - lh, m3 = m1 + m2;
                if (m3 >= -2 && m3 <= 2) stab[i1][i2] = su2cg(la, m1, lh, m2, 2, m3);
            }
        for (int i = 0; i < 2*la+1; ++i) {
            int r1[2]{}; CD v1[2]{}; const int n1 = q_col(la, i, r1, v1);
            for (int j = 0; j < 2*lh+1; ++j) {
                int r2[2]{}; CD v2[2]{}; const int n2 = q_col(lh, j, r2, v2);
                double outk[5]{};
                bool any = false;
                for (int k = 0; k < 5; ++k) {
                    double acc = 0.0;
                    for (int a = 0; a < n1; ++a)
                        for (int b = 0; b < n2; ++b) {
                            const int m3 = (r1[a] - la) + (r2[b] - lh);
                            for (int q = 0; q < n3[k]; ++q) {
                                if (r3[k][q] - 2 != m3) continue;
                                CD t = cmul(v1[a], v2[b]);
                                acc += (t.re * v3[k][q].re + t.im * v3[k][q].im)
                                       * stab[r1[a]][r2[b]];   // Re(Q1 Q2 conj(Q3)) * su2cg
                            }
                        }
                    outk[k] = acc;
                    if (acc != 0.0) any = true;
                }
                if (any) {
                    T.idx[e] = (ABASE[la] + i) | ((ABASE[lh] + j) << 8) | (c << 16);
                    for (int k = 0; k < 4; ++k) T.cg4[e][k] = (float)outk[k];
                    T.cg1[e] = (float)outk[4];
                    ++e;
                }
            }
        }
    }
    T.n = e;
    // pad region already zero from value-init: idx=0 -> p*0 contribution
    return T;
}

constexpr Tables T_HOST = build();
constexpr int N_ENT = T_HOST.n;
constexpr int NIT = (N_ENT + 63) / 64;   // compile-time trip count, branch-free

} // namespace cgc

__device__ const cgc::Tables g_tab = cgc::T_HOST;

__global__ __launch_bounds__(64) void cgweight_kernel(
    const float* __restrict__ a0, const float* __restrict__ a1,
    const float* __restrict__ a2, const float* __restrict__ a3,
    const float* __restrict__ a4,
    const float* __restrict__ h0, const float* __restrict__ h1,
    const float* __restrict__ h2, const float* __restrict__ h3,
    const float* __restrict__ h4,
    const float* __restrict__ w, float* __restrict__ out) {

    const int t = threadIdx.x;   // one 64-lane wave, no LDS, no barriers

    // ---- per-lane input slot: branchless pointer SELECT, then one load ----
    // lane t<25 holds Acat[t] (concat of a0..a4), likewise Hcat; lane t holds w[t&15]
    const float* ap = a0; int ao = 0;
    if (t >= 1  && t < 4)  { ap = a1; ao = t - 1; }
    if (t >= 4  && t < 9)  { ap = a2; ao = t - 4; }
    if (t >= 9  && t < 16) { ap = a3; ao = t - 9; }
    if (t >= 16 && t < 25) { ap = a4; ao = t - 16; }
    const float* hp = h0; int ho = 0;
    if (t >= 1  && t < 4)  { hp = h1; ho = t - 1; }
    if (t >= 4  && t < 9)  { hp = h2; ho = t - 4; }
    if (t >= 9  && t < 16) { hp = h3; ho = t - 9; }
    if (t >= 16 && t < 25) { hp = h4; ho = t - 16; }

    const float va = ap[ao];        // 3 input loads issued first (oldest)
    const float vh = hp[ho];
    const float vw = w[t & 15];

    // ---- branch-free table loads: all 3*NIT issued back-to-back ----
    int    id[cgc::NIT];
    float4 q4[cgc::NIT];
    float  q1[cgc::NIT];
#pragma unroll
    for (int it = 0; it < cgc::NIT; ++it) {
        const int e = t + 64 * it;            // < MAXP, pad entries are zero
        id[it] = g_tab.idx[e];
        q4[it] = *reinterpret_cast<const float4*>(g_tab.cg4[e]);
        q1[it] = g_tab.cg1[e];
    }

    // ---- compute: in-wave shuffle gather + FMAs ----
    float c0 = 0.f, c1 = 0.f, c2 = 0.f, c3 = 0.f, c4 = 0.f;
#pragma unroll
    for (int it = 0; it < cgc::NIT; ++it) {
        const int i  = id[it];
        const float ga = __shfl(va, i & 255, 64);
        const float gh = __shfl(vh, (i >> 8) & 255, 64);
        const float gw = __shfl(vw, i >> 16, 64);
        const float p  = ga * gh * gw;
        c0 += q4[it].x * p;
        c1 += q4[it].y * p;
        c2 += q4[it].z * p;
        c3 += q4[it].w * p;
        c4 += q1[it]   * p;
    }

    // ---- 64-lane butterfly reduce, lane 0 stores ----
    float acc[5] = {c0, c1, c2, c3, c4};
#pragma unroll
    for (int k = 0; k < 5; ++k) {
        float v = acc[k];
#pragma unroll
        for (int off = 32; off > 0; off >>= 1)
            v += __shfl_down(v, off, 64);
        acc[k] = v;
    }

    if (t == 0) {
#pragma unroll
        for (int k = 0; k < 5; ++k) {
            const float f = acc[k];
            out[k] = (f != f) ? 0.0f : f;   // nan_to_num
        }
    }
}

extern "C" void kernel_launch(void* const* d_in, const int* in_sizes, int n_in,
                              void* d_out, int out_size, void* d_ws, size_t ws_size,
                              hipStream_t stream) {
    const float* a0 = (const float*)d_in[0];
    const float* a1 = (const float*)d_in[1];
    const float* a2 = (const float*)d_in[2];
    const float* a3 = (const float*)d_in[3];
    const float* a4 = (const float*)d_in[4];
    const float* h0 = (const float*)d_in[5];
    const float* h1 = (const float*)d_in[6];
    const float* h2 = (const float*)d_in[7];
    const float* h3 = (const float*)d_in[8];
    const float* h4 = (const float*)d_in[9];
    const float* w  = (const float*)d_in[10];
    float* out = (float*)d_out;

    cgweight_kernel<<<1, 64, 0, stream>>>(a0, a1, a2, a3, a4,
                                          h0, h1, h2, h3, h4, w, out);
}